// Round 10
// baseline (531.825 us; speedup 1.0000x reference)
//
#include <hip/hip_runtime.h>

// ---------------------------------------------------------------------------
// MixtralAttention on MI355X (gfx950)
// B=2, S=2048, HID=4096, NH=32, NKV=8, HD=128, WINDOW=1024, THETA=10000
// Stages: cvt1(wqkvT+hs) -> GEMM1(qkv, 256x192, A-3buf/B-2buf, grid 512)
//         -> rope_cvtwo -> flash attn -> GEMM2(out, 256x256 2buf, grid 256)
// GEMM1 (new): asymmetric triple-buffer. A staged 2 tiles ahead (stream,
// long latency), B 1 tile ahead (L2-shared panel). Tile-entry wait is
// vmcnt(4) (counted, never drains the A(t+1) prefetch) instead of vmcnt(0).
// ---------------------------------------------------------------------------

typedef __attribute__((ext_vector_type(8))) short short8;       // bf16x8 frag
typedef __attribute__((ext_vector_type(4))) float f32x4;        // 16x16 acc
typedef __attribute__((ext_vector_type(16))) float f32x16;      // 32x32 acc
typedef __attribute__((ext_vector_type(4))) unsigned int u32x4; // 16B load
typedef __attribute__((ext_vector_type(4))) unsigned short u16x4;

__device__ __forceinline__ unsigned short f2bf(float f) {
  unsigned int u = __builtin_bit_cast(unsigned int, f);
  u = u + 0x7fffu + ((u >> 16) & 1u);   // round-to-nearest-even
  return (unsigned short)(u >> 16);
}
__device__ __forceinline__ float bf2f(unsigned short h) {
  unsigned int u = ((unsigned int)h) << 16;
  return __builtin_bit_cast(float, u);
}
__device__ __forceinline__ unsigned int cvtpk_bf16(float lo, float hi) {
  unsigned int r;
  asm("v_cvt_pk_bf16_f32 %0, %1, %2" : "=v"(r) : "v"(lo), "v"(hi));
  return r;
}

__device__ __forceinline__ void gload_lds16(const unsigned short* g, unsigned short* l) {
  __builtin_amdgcn_global_load_lds(
      (const __attribute__((address_space(1))) unsigned int*)g,
      (__attribute__((address_space(3))) unsigned int*)l, 16, 0, 0);
}

// barrier that drains LDS ops only -- keeps global prefetch loads in flight
__device__ __forceinline__ void lds_barrier() {
  asm volatile("s_waitcnt lgkmcnt(0)" ::: "memory");
  __builtin_amdgcn_s_barrier();
}

#define MFMA16(A, B, C) __builtin_amdgcn_mfma_f32_16x16x32_bf16((A), (B), (C), 0, 0, 0)
#define MFMA32(A, B, C) __builtin_amdgcn_mfma_f32_32x32x16_bf16((A), (B), (C), 0, 0, 0)
#define BC8(x) __builtin_bit_cast(short8, (x))

// ---------------------------------------------------------------------------
// merged: cvt_t(wqkv -> wqkvT) + cvt_plain(hs -> hsb)
// ---------------------------------------------------------------------------
__global__ __launch_bounds__(256) void cvt1(const float* __restrict__ hs,
                                            const float* __restrict__ wqkv,
                                            unsigned short* __restrict__ hsb,
                                            unsigned short* __restrict__ wT) {
  const int bid = blockIdx.x;
  if (bid < 24576) {
    __shared__ float t[32][33];
    const int c0 = (bid % 192) * 32, r0 = (bid / 192) * 32;  // R=4096, C=6144
    const int tx = threadIdx.x & 31, ty = threadIdx.x >> 5;
#pragma unroll
    for (int i = 0; i < 4; ++i)
      t[ty + i * 8][tx] = wqkv[(size_t)(r0 + ty + i * 8) * 6144 + c0 + tx];
    __syncthreads();
#pragma unroll
    for (int i = 0; i < 4; ++i)
      wT[(size_t)(c0 + ty + i * 8) * 4096 + r0 + tx] = f2bf(t[tx][ty + i * 8]);
  } else {
    const int i = ((bid - 24576) * 256 + threadIdx.x) * 4;
    f32x4 v = *(const f32x4*)(hs + i);
    u16x4 o;
#pragma unroll
    for (int j = 0; j < 4; ++j) o[j] = f2bf(v[j]);
    *(u16x4*)(hsb + i) = o;
  }
}

// ---------------------------------------------------------------------------
// merged: rope_k (K heads in qkv) + cvt_t(wo -> woT)
// ---------------------------------------------------------------------------
__global__ __launch_bounds__(256) void rope_cvtwo(unsigned short* __restrict__ qkv,
                                                  const int* __restrict__ pos,
                                                  const float* __restrict__ wo,
                                                  unsigned short* __restrict__ wT) {
  const int bid = blockIdx.x;
  if (bid < 8192) {
    const int idx = bid * 256 + threadIdx.x;   // < 4096*8*64
    const int d = idx & 63;
    const int hh = (idx >> 6) & 7;
    const int tok = idx >> 9;
    const int s = tok & 2047;
    unsigned short* p = qkv + (size_t)tok * 6144 + 4096 + hh * 128 + d;
    const float x1 = bf2f(p[0]);
    const float x2 = bf2f(p[64]);
    const float inv = exp2f(-(float)d * 0.2076205059304601f);
    const float ang = (float)pos[s] * inv;
    const float c = cosf(ang), sn = sinf(ang);
    p[0]  = f2bf(x1 * c - x2 * sn);
    p[64] = f2bf(x2 * c + x1 * sn);
  } else {
    __shared__ float t[32][33];
    const int b2 = bid - 8192;
    const int c0 = (b2 % 128) * 32, r0 = (b2 / 128) * 32;   // R=C=4096
    const int tx = threadIdx.x & 31, ty = threadIdx.x >> 5;
#pragma unroll
    for (int i = 0; i < 4; ++i)
      t[ty + i * 8][tx] = wo[(size_t)(r0 + ty + i * 8) * 4096 + c0 + tx];
    __syncthreads();
#pragma unroll
    for (int i = 0; i < 4; ++i)
      wT[(size_t)(c0 + ty + i * 8) * 4096 + r0 + tx] = f2bf(t[tx][ty + i * 8]);
  }
}

// ---------------------------------------------------------------------------
// GEMM1: C[M,N] = A[M,K] * B^T[N,K], tile 256x192 (NIF=3), grid 512.
// Asymmetric buffering: aB[3] (A[256][64] each, 32 KB), bB[2] (B[192][64],
// 24 KB) = 144 KB LDS. Per K-tile t:
//   entry: vmcnt(4) [A(t),B(t) landed; A(t+1) stays in flight] + s_barrier
//   issue: B(t+1) -> bB[(t+1)&1], A(t+2) -> aB[(t+2)%3]
//   P0: B frags + A mi0-2 | P1: mi3-5 | P2: mi6-7 (bare barriers between)
// Queue ledger: prologue issues A(0),B(0),A(1); steady-state queue at entry
// = {A(t):4, B(t):3, A(t+1):4} -> vmcnt(4). Last tile: vmcnt(0).
// ---------------------------------------------------------------------------
__global__ __launch_bounds__(512, 2) void gemm_qkv(const unsigned short* __restrict__ A,
                                                   const unsigned short* __restrict__ BT,
                                                   unsigned short* __restrict__ Cout,
                                                   int M, int N, int K) {
  __shared__ __align__(16) unsigned short aB[3][16384];   // 96 KB
  __shared__ __align__(16) unsigned short bB[2][12288];   // 48 KB
  const int tid = threadIdx.x;
  const int lane = tid & 63;
  const int w = tid >> 6;
  const int wr = w >> 2;
  const int wc = w & 3;
  const int g = lane >> 4;
  const int l15 = lane & 15;

  const int nwg = gridDim.x;
  const int cpx = nwg >> 3;
  const int bid = blockIdx.x;
  const int swz = (bid & 7) * cpx + (bid >> 3);
  const int MT = M >> 8;
  const int m0 = (swz % MT) * 256;
  const int n0 = (swz / MT) * 192;

  const int lrow = lane >> 3;
  const int lcol = ((lane & 7) ^ lrow) * 8;
  const unsigned short* Asrc = A + (size_t)(m0 + w * 8 + lrow) * K + lcol;
  const unsigned short* Bsrc = BT + (size_t)(n0 + w * 8 + lrow) * K + lcol;

  f32x4 acc[8][3] = {};

  auto stageA = [&](int buf, int t) {
#pragma unroll
    for (int j = 0; j < 4; ++j) {
      const int rb = (j & 1) * 128 + ((j >> 1) & 1) * 64;
      gload_lds16(Asrc + (size_t)rb * K + t * 64, &aB[buf][(rb + w * 8) * 64]);
    }
  };
  auto stageB = [&](int buf, int t) {
#pragma unroll
    for (int r = 0; r < 3; ++r)
      gload_lds16(Bsrc + (size_t)(r * 64) * K + t * 64,
                  &bB[buf][(r * 64 + w * 8) * 64]);
  };
  auto rdA = [&](int buf, int mi, int ks) {
    const int row = wr * 128 + mi * 16 + l15;
    const int cb = (ks * 64 + g * 16) ^ ((l15 & 7) << 4);
    return *(const u32x4*)((const char*)&aB[buf][0] + row * 128 + cb);
  };
  auto rdB = [&](int buf, int ni, int ks) {
    const int row = wc * 48 + ni * 16 + l15;
    const int cb = (ks * 64 + g * 16) ^ ((l15 & 7) << 4);
    return *(const u32x4*)((const char*)&bB[buf][0] + row * 128 + cb);
  };

  // prologue: A(0) [4], B(0) [3], A(1) [4]  -- order defines the vmcnt queue
  stageA(0, 0);
  stageB(0, 0);
  stageA(1, 1);

  const int NT = K >> 6;
  int cbA = 0;
  for (int t = 0; t < NT; ++t) {
    const int cbB = t & 1;

    // ---- tile entry: counted wait (A(t+1) stays in flight) ----
    if (t + 1 < NT) {
      asm volatile("s_waitcnt vmcnt(4)" ::: "memory");
    } else {
      asm volatile("s_waitcnt vmcnt(0)" ::: "memory");
    }
    __builtin_amdgcn_s_barrier();
    asm volatile("" ::: "memory");
    if (t + 1 < NT) stageB(cbB ^ 1, t + 1);
    if (t + 2 < NT) stageA((cbA + 2) % 3, t + 2);

    u32x4 bfr[3][2];
#pragma unroll
    for (int ni = 0; ni < 3; ++ni) {
      bfr[ni][0] = rdB(cbB, ni, 0);
      bfr[ni][1] = rdB(cbB, ni, 1);
    }

    // ---------------- P0 : mi 0,1,2 ----------------
    {
      u32x4 af[3][2];
#pragma unroll
      for (int mi = 0; mi < 3; ++mi) {
        af[mi][0] = rdA(cbA, mi, 0);
        af[mi][1] = rdA(cbA, mi, 1);
      }
      __builtin_amdgcn_s_setprio(1);
#pragma unroll
      for (int mi = 0; mi < 3; ++mi)
#pragma unroll
        for (int ni = 0; ni < 3; ++ni) {
          acc[mi][ni] = MFMA16(BC8(af[mi][0]), BC8(bfr[ni][0]), acc[mi][ni]);
          acc[mi][ni] = MFMA16(BC8(af[mi][1]), BC8(bfr[ni][1]), acc[mi][ni]);
        }
      __builtin_amdgcn_s_setprio(0);
    }
    __builtin_amdgcn_s_barrier();
    // ---------------- P1 : mi 3,4,5 ----------------
    {
      u32x4 af[3][2];
#pragma unroll
      for (int mi = 0; mi < 3; ++mi) {
        af[mi][0] = rdA(cbA, 3 + mi, 0);
        af[mi][1] = rdA(cbA, 3 + mi, 1);
      }
      __builtin_amdgcn_s_setprio(1);
#pragma unroll
      for (int mi = 0; mi < 3; ++mi)
#pragma unroll
        for (int ni = 0; ni < 3; ++ni) {
          acc[3 + mi][ni] = MFMA16(BC8(af[mi][0]), BC8(bfr[ni][0]), acc[3 + mi][ni]);
          acc[3 + mi][ni] = MFMA16(BC8(af[mi][1]), BC8(bfr[ni][1]), acc[3 + mi][ni]);
        }
      __builtin_amdgcn_s_setprio(0);
    }
    __builtin_amdgcn_s_barrier();
    // ---------------- P2 : mi 6,7 ----------------
    {
      u32x4 af[2][2];
#pragma unroll
      for (int mi = 0; mi < 2; ++mi) {
        af[mi][0] = rdA(cbA, 6 + mi, 0);
        af[mi][1] = rdA(cbA, 6 + mi, 1);
      }
      __builtin_amdgcn_s_setprio(1);
#pragma unroll
      for (int mi = 0; mi < 2; ++mi)
#pragma unroll
        for (int ni = 0; ni < 3; ++ni) {
          acc[6 + mi][ni] = MFMA16(BC8(af[mi][0]), BC8(bfr[ni][0]), acc[6 + mi][ni]);
          acc[6 + mi][ni] = MFMA16(BC8(af[mi][1]), BC8(bfr[ni][1]), acc[6 + mi][ni]);
        }
      __builtin_amdgcn_s_setprio(0);
    }
    cbA = (cbA + 1) % 3;
    // next iteration's entry wait+barrier is the sync point
  }

  const int crow0 = m0 + wr * 128;
  const int ccol0 = n0 + wc * 48;
#pragma unroll
  for (int mi = 0; mi < 8; ++mi)
#pragma unroll
    for (int ni = 0; ni < 3; ++ni)
#pragma unroll
      for (int r = 0; r < 4; ++r) {
        const size_t idx =
            (size_t)(crow0 + mi * 16 + g * 4 + r) * N + (ccol0 + ni * 16 + l15);
        Cout[idx] = f2bf(acc[mi][ni][r]);
      }
}

// ---------------------------------------------------------------------------
// GEMM2: C[M,N] = A[M,K] * B^T[N,K]  -- R9 single-sync 2-buffer (unchanged)
// Tile 256x256 (NIF=4), grid 256.
// ---------------------------------------------------------------------------
__global__ __launch_bounds__(512, 2) void gemm256(const unsigned short* __restrict__ A,
                                                  const unsigned short* __restrict__ BT,
                                                  float* __restrict__ Cout,
                                                  int M, int N, int K) {
  __shared__ __align__(16) unsigned short lds[2][32768];
  const int tid = threadIdx.x;
  const int lane = tid & 63;
  const int w = tid >> 6;
  const int wr = w >> 2;
  const int wc = w & 3;
  const int g = lane >> 4;
  const int l15 = lane & 15;

  const int nwg = gridDim.x;
  const int cpx = nwg >> 3;
  const int bid = blockIdx.x;
  const int swz = (bid & 7) * cpx + (bid >> 3);
  const int MT = M >> 8;
  const int m0 = (swz % MT) * 256;
  const int n0 = (swz / MT) * 256;

  const int lrow = lane >> 3;
  const int lcol = ((lane & 7) ^ lrow) * 8;
  const unsigned short* Asrc = A + (size_t)(m0 + w * 8 + lrow) * K + lcol;
  const unsigned short* Bsrc = BT + (size_t)(n0 + w * 8 + lrow) * K + lcol;

  f32x4 acc[8][4] = {};

  auto stage = [&](int buf, int t, int r) {
    if (r < 4) {
      const int rb = r * 64;
      gload_lds16(Bsrc + (size_t)rb * K + t * 64,
                  &lds[buf][16384 + (rb + w * 8) * 64]);
    } else {
      const int j = r - 4;
      const int rb = (j & 1) * 128 + ((j >> 1) & 1) * 64;
      gload_lds16(Asrc + (size_t)rb * K + t * 64,
                  &lds[buf][(rb + w * 8) * 64]);
    }
  };
  auto rdA = [&](int buf, int mi, int ks) {
    const int row = wr * 128 + mi * 16 + l15;
    const int cb = (ks * 64 + g * 16) ^ ((l15 & 7) << 4);
    return *(const u32x4*)((const char*)&lds[buf][0] + row * 128 + cb);
  };
  auto rdB = [&](int buf, int ni, int ks) {
    const int row = wc * 64 + ni * 16 + l15;
    const int cb = (ks * 64 + g * 16) ^ ((l15 & 7) << 4);
    return *(const u32x4*)((const char*)&lds[buf][0] + 32768 + row * 128 + cb);
  };

#pragma unroll
  for (int r = 0; r < 8; ++r) stage(0, 0, r);

  const int NT = K >> 6;
  for (int t = 0; t < NT; ++t) {
    const int cb_ = t & 1, nb_ = cb_ ^ 1;

    asm volatile("s_waitcnt vmcnt(0)" ::: "memory");
    __builtin_amdgcn_s_barrier();
    asm volatile("" ::: "memory");
    if (t + 1 < NT) {
#pragma unroll
      for (int r = 0; r < 8; ++r) stage(nb_, t + 1, r);
    }

    u32x4 bfr[4][2];
#pragma unroll
    for (int ni = 0; ni < 4; ++ni) {
      bfr[ni][0] = rdB(cb_, ni, 0);
      bfr[ni][1] = rdB(cb_, ni, 1);
    }

    {
      u32x4 af[3][2];
#pragma unroll
      for (int mi = 0; mi < 3; ++mi) {
        af[mi][0] = rdA(cb_, mi, 0);
        af[mi][1] = rdA(cb_, mi, 1);
      }
      __builtin_amdgcn_s_setprio(1);
#pragma unroll
      for (int mi = 0; mi < 3; ++mi)
#pragma unroll
        for (int ni = 0; ni < 4; ++ni) {
          acc[mi][ni] = MFMA16(BC8(af[mi][0]), BC8(bfr[ni][0]), acc[mi][ni]);
          acc[mi][ni] = MFMA16(BC8(af[mi][1]), BC8(bfr[ni][1]), acc[mi][ni]);
        }
      __builtin_amdgcn_s_setprio(0);
    }
    __builtin_amdgcn_s_barrier();
    {
      u32x4 af[3][2];
#pragma unroll
      for (int mi = 0; mi < 3; ++mi) {
        af[mi][0] = rdA(cb_, 3 + mi, 0);
        af[mi][1] = rdA(cb_, 3 + mi, 1);
      }
      __builtin_amdgcn_s_setprio(1);
#pragma unroll
      for (int mi = 0; mi < 3; ++mi)
#pragma unroll
        for (int ni = 0; ni < 4; ++ni) {
          acc[3 + mi][ni] = MFMA16(BC8(af[mi][0]), BC8(bfr[ni][0]), acc[3 + mi][ni]);
          acc[3 + mi][ni] = MFMA16(BC8(af[mi][1]), BC8(bfr[ni][1]), acc[3 + mi][ni]);
        }
      __builtin_amdgcn_s_setprio(0);
    }
    __builtin_amdgcn_s_barrier();
    {
      u32x4 af[2][2];
#pragma unroll
      for (int mi = 0; mi < 2; ++mi) {
        af[mi][0] = rdA(cb_, 6 + mi, 0);
        af[mi][1] = rdA(cb_, 6 + mi, 1);
      }
      __builtin_amdgcn_s_setprio(1);
#pragma unroll
      for (int mi = 0; mi < 2; ++mi)
#pragma unroll
        for (int ni = 0; ni < 4; ++ni) {
          acc[6 + mi][ni] = MFMA16(BC8(af[mi][0]), BC8(bfr[ni][0]), acc[6 + mi][ni]);
          acc[6 + mi][ni] = MFMA16(BC8(af[mi][1]), BC8(bfr[ni][1]), acc[6 + mi][ni]);
        }
      __builtin_amdgcn_s_setprio(0);
    }
  }

  const int crow0 = m0 + wr * 128;
  const int ccol0 = n0 + wc * 64;
#pragma unroll
  for (int mi = 0; mi < 8; ++mi)
#pragma unroll
    for (int ni = 0; ni < 4; ++ni)
#pragma unroll
      for (int r = 0; r < 4; ++r) {
        const size_t idx =
            (size_t)(crow0 + mi * 16 + g * 4 + r) * N + (ccol0 + ni * 16 + l15);
        Cout[idx] = acc[mi][ni][r];
      }
}

// ---------------------------------------------------------------------------
// Flash attention, GQA, causal + sliding window 1024, fused Q-RoPE.
// (unchanged from R9)
// ---------------------------------------------------------------------------
__global__ __launch_bounds__(512, 2) void attn_kernel(const unsigned short* __restrict__ qkv,
                                                      unsigned short* __restrict__ aout,
                                                      const int* __restrict__ pos) {
  __shared__ __align__(16) unsigned short smem[35840];   // 2 buffers, 70 KiB

  const int tid = threadIdx.x;
  const int lane = tid & 63;
  const int w = tid >> 6;
  const int hi = lane >> 5;
  const int l31 = lane & 31;
  const int q0 = blockIdx.x * 256;
  const int h = blockIdx.y;
  const int b = blockIdx.z;
  const int kh = h >> 2;
  const size_t tokbase = (size_t)b * 2048;
  const int qw0 = q0 + w * 32;
  const int qg = qw0 + l31;

  short8 qf[8];
  {
    const unsigned short* qp = qkv + (tokbase + qg) * 6144 + h * 128;
#pragma unroll
    for (int ks8 = 0; ks8 < 8; ++ks8)
      qf[ks8] = BC8(*(const u32x4*)(qp + ks8 * 16 + hi * 8));
    const float fp = (float)pos[qg];
#pragma unroll
    for (int ks8 = 0; ks8 < 4; ++ks8)
#pragma unroll
      for (int j = 0; j < 8; ++j) {
        const int d = ks8 * 16 + hi * 8 + j;
        const float x1 = bf2f((unsigned short)qf[ks8][j]);
        const float x2 = bf2f((unsigned short)qf[ks8 + 4][j]);
        const float ang = fp * exp2f(-(float)d * 0.2076205059304601f);
        float c, sn;
        __sincosf(ang, &sn, &c);
        c *= 0.12751743f; sn *= 0.12751743f;   // scale * log2(e)
        qf[ks8][j]     = (short)f2bf(x1 * c - x2 * sn);
        qf[ks8 + 4][j] = (short)f2bf(x2 * c + x1 * sn);
      }
  }

  const int c0key = tid >> 4, c0col = tid & 15;
  const int c1key = (tid + 512) >> 4, c1col = tid & 15;

  u32x4 kreg[2], vreg[2];
  const unsigned short* kvK = qkv + tokbase * 6144 + 4096 + kh * 128;

  const int t0 = (q0 >= 1024 ? (q0 - 1023) >> 6 : 0);
  const int t1 = (q0 + 255) >> 6;

  {
    const unsigned short* kb = kvK + (size_t)(t0 * 64) * 6144;
    kreg[0] = *(const u32x4*)(kb + (size_t)c0key * 6144 + c0col * 8);
    kreg[1] = *(const u32x4*)(kb + (size_t)c1key * 6144 + c1col * 8);
    vreg[0] = *(const u32x4*)(kb + (size_t)c0key * 6144 + 1024 + c0col * 8);
    vreg[1] = *(const u32x4*)(kb + (size_t)c1key * 6144 + 1024 + c1col * 8);
  }

  float m_run = -1e30f, l_run = 0.0f;
  f32x16 o_acc[4] = {};

  for (int kt = t0; kt <= t1; ++kt) {
    const int cur = (kt - t0) & 1;
    unsigned short* kdst = &smem[(cur)*17920];
    unsigned short* vdst = kdst + 8704;

    if (kt == t0) {
      *(u32x4*)&kdst[c0key * 136 + c0col * 8] = kreg[0];
      *(u32x4*)&kdst[c1key * 136 + c1col * 8] = kreg[1];
#pragma unroll
      for (int e = 0; e < 8; ++e) {
        const int e0 = (e + c0col) & 7;
        const int e1 = (e + c1col) & 7;
        vdst[(c0col * 8 + e0) * 72 + c0key] =
            (unsigned short)(vreg[0][e0 >> 1] >> ((e0 & 1) * 16));
        vdst[(c1col * 8 + e1) * 72 + c1key] =
            (unsigned short)(vreg[1][e1 >> 1] >> ((e1 & 1) * 16));
      }
      if (kt < t1) {
        const unsigned short* kb = kvK + (size_t)((kt + 1) * 64) * 6144;
        kreg[0] = *(const u32x4*)(kb + (size_t)c0key * 6144 + c0col * 8);
        kreg[1] = *(const u32x4*)(kb + (size_t)c1key * 6144 + c1col * 8);
        vreg[0] = *(const u32x4*)(kb + (size_t)c0key * 6144 + 1024 + c0col * 8);
        vreg[1] = *(const u32x4*)(kb + (size_t)c1key * 6144 + 1024 + c1col * 8);
      }
      lds_barrier();
    }

    if (kt < t1) {
      unsigned short* kdn = &smem[(cur ^ 1) * 17920];
      unsigned short* vdn = kdn + 8704;
      *(u32x4*)&kdn[c0key * 136 + c0col * 8] = kreg[0];
      *(u32x4*)&kdn[c1key * 136 + c1col * 8] = kreg[1];
#pragma unroll
      for (int e = 0; e < 8; ++e) {
        const int e0 = (e + c0col) & 7;
        const int e1 = (e + c1col) & 7;
        vdn[(c0col * 8 + e0) * 72 + c0key] =
            (unsigned short)(vreg[0][e0 >> 1] >> ((e0 & 1) * 16));
        vdn[(c1col * 8 + e1) * 72 + c1key] =
            (unsigned short)(vreg[1][e1 >> 1] >> ((e1 & 1) * 16));
      }
      if (kt + 2 <= t1) {
        const unsigned short* kb = kvK + (size_t)((kt + 2) * 64) * 6144;
        kreg[0] = *(const u32x4*)(kb + (size_t)c0key * 6144 + c0col * 8);
        kreg[1] = *(const u32x4*)(kb + (size_t)c1key * 6144 + c1col * 8);
        vreg[0] = *(const u32x4*)(kb + (size_t)c0key * 6144 + 1024 + c0col * 8);
        vreg[1] = *(const u32x4*)(kb + (size_t)c1key * 6144 + 1024 + c1col * 8);
      }
    }

    const int ktb = kt * 64;
    if (ktb <= qw0 + 31 && ktb + 63 >= qw0 - 1023) {
      const unsigned short* kb = &smem[cur * 17920];
      const unsigned short* vb = kb + 8704;

      f32x16 s0 = {}, s1 = {};
      const int arow = l31 * 136 + hi * 8;
#pragma unroll
      for (int ks8 = 0; ks8 < 8; ++ks8) {
        u32x4 a0 = *(const u32x4*)&kb[arow + ks8 * 16];
        u32x4 a1 = *(const u32x4*)&kb[arow + 32 * 136 + ks8 * 16];
        s0 = MFMA32(BC8(a0), qf[ks8], s0);
        s1 = MFMA32(BC8(a1), qf[ks8], s1);
      }

      float pv[32];
      const bool need_mask = !(ktb + 63 <= qw0 && ktb >= qw0 - 992);
      if (need_mask) {
#pragma unroll
        for (int r = 0; r < 16; ++r) {
          const int key0 = ktb + ((r & 3) + 8 * (r >> 2) + 4 * hi);
          const int key1 = key0 + 32;
          pv[r]      = (key0 <= qg && qg - key0 < 1024) ? s0[r] : -1e30f;
          pv[16 + r] = (key1 <= qg && qg - key1 < 1024) ? s1[r] : -1e30f;
        }
      } else {
#pragma unroll
        for (int r = 0; r < 16; ++r) {
          pv[r] = s0[r];
          pv[16 + r] = s1[r];
        }
      }

      float mx[16];
#pragma unroll
      for (int i = 0; i < 16; ++i) mx[i] = fmaxf(pv[i], pv[i + 16]);
#pragma unroll
      for (int i = 0; i < 8; ++i) mx[i] = fmaxf(mx[i], mx[i + 8]);
#pragma unroll
      for (int i = 0; i < 4; ++i) mx[i] = fmaxf(mx[i], mx[i + 4]);
      float tm = fmaxf(fmaxf(mx[0], mx[1]), fmaxf(mx[2], mx[3]));
      tm = fmaxf(tm, __shfl_xor(tm, 32, 64));
      if (__any(tm > m_run + 11.5415603f)) {       // 8 * log2(e)
        const float mn = fmaxf(fmaxf(m_run, tm), -1e20f);
        const float scl = exp2f(m_run - mn);
#pragma unroll
        for (int d = 0; d < 4; ++d) o_acc[d] *= scl;
        l_run *= scl;
        m_run = mn;
      }
#pragma unroll
      for (int i = 0; i < 32; ++i) pv[i] = exp2f(pv[i] - m_run);
      float sm[16];
#pragma unroll
      for (int i = 0; i < 16; ++i) sm[i] = pv[i] + pv[i + 16];
#pragma unroll
      for (int i = 0; i < 8; ++i) sm[i] = sm[i] + sm[i + 8];
#pragma unroll
      for (int i = 0; i < 4; ++i) sm[i] = sm[i] + sm[i + 4];
      float lsum = (sm[0] + sm[1]) + (sm[2] + sm[3]);
      l_run += lsum + __shfl_xor(lsum, 32, 64);

      u32x4 paf[4];
#pragma unroll
      for (int ks = 0; ks < 4; ++ks) {
        const int base = (ks >> 1) * 16 + (ks & 1) * 8;
        auto rA = __builtin_amdgcn_permlane32_swap(
            (int)cvtpk_bf16(pv[base + 0], pv[base + 1]),
            (int)cvtpk_bf16(pv[base + 4], pv[base + 5]), false, false);
        auto rB = __builtin_amdgcn_permlane32_swap(
            (int)cvtpk_bf16(pv[base + 2], pv[base + 3]),
            (int)cvtpk_bf16(pv[base + 6], pv[base + 7]), false, false);
        paf[ks][0] = (unsigned int)rA[0];
        paf[ks][1] = (unsigned int)rB[0];
        paf[ks][2] = (unsigned int)rA[1];
        paf[ks][3] = (unsigned int)rB[1];
      }

#pragma unroll
      for (int dblk = 0; dblk < 4; ++dblk) {
        const int vrow = (dblk * 32 + l31) * 72 + hi * 8;
#pragma unroll
        for (int ks = 0; ks < 4; ++ks) {
          u32x4 vf = *(const u32x4*)&vb[vrow + ks * 16];
          o_acc[dblk] = MFMA32(BC8(vf), BC8(paf[ks]), o_acc[dblk]);
        }
      }
    }

    lds_barrier();
  }

  const float rl = 1.0f / l_run;
  unsigned short* ob = &smem[w * 4352];
#pragma unroll
  for (int dblk = 0; dblk < 4; ++dblk)
#pragma unroll
    for (int rq = 0; rq < 4; ++rq) {
      u16x4 pk;
#pragma unroll
      for (int i = 0; i < 4; ++i) pk[i] = f2bf(o_acc[dblk][rq * 4 + i] * rl);
      *(u16x4*)&ob[l31 * 136 + dblk * 32 + rq * 8 + hi * 4] = pk;
    }
  lds_barrier();

  unsigned short* gout = aout + (tokbase + q0 + w * 32) * 4096 + h * 128;
#pragma unroll
  for (int r4 = 0; r4 < 8; ++r4) {
    const int row = r4 * 4 + (lane >> 4);
    u32x4 val = *(const u32x4*)&ob[row * 136 + (lane & 15) * 8];
    *(u32x4*)(gout + (size_t)row * 4096 + (lane & 15) * 8) = val;
  }
}

// ---------------------------------------------------------------------------
// launch
// ---------------------------------------------------------------------------
extern "C" void kernel_launch(void* const* d_in, const int* in_sizes, int n_in,
                              void* d_out, int out_size, void* d_ws, size_t ws_size,
                              hipStream_t stream) {
  (void)in_sizes; (void)n_in; (void)out_size; (void)ws_size;
  const float* hs   = (const float*)d_in[0];   // [2,2048,4096]
  const float* wqkv = (const float*)d_in[1];   // [4096,6144]
  const float* wo   = (const float*)d_in[2];   // [4096,4096]
  const int*   pos  = (const int*)d_in[3];     // [2048]
  float* out = (float*)d_out;                  // [2,2048,4096] fp32

  char* ws = (char*)d_ws;
  unsigned short* qkvb = (unsigned short*)ws;                // [4096][6144] bf16
  unsigned short* wT   = (unsigned short*)(ws + 50331648);   // weightT bf16
  unsigned short* hsb  = (unsigned short*)(ws + 100663296);  // [4096][4096] bf16

  cvt1<<<40960, 256, 0, stream>>>(hs, wqkv, hsb, wT);
  // GEMM1: tile 256x192, A-3buf/B-2buf, grid 512 = 2.0 CU-waves
  gemm_qkv<<<512, 512, 0, stream>>>(hsb, wT, qkvb, 4096, 6144, 4096);
  rope_cvtwo<<<24576, 256, 0, stream>>>(qkvb, pos, wo, wT);
  attn_kernel<<<dim3(8, 32, 2), 512, 0, stream>>>(qkvb, hsb, pos);
  // GEMM2: tile 256x256, grid 256 = 1.0 CU-wave
  gemm256<<<256, 512, 0, stream>>>(hsb, wT, out, 4096, 4096, 4096);
}

// Round 11
// 475.403 us; speedup vs baseline: 1.1187x; 1.1187x over previous
//
#include <hip/hip_runtime.h>

// ---------------------------------------------------------------------------
// MixtralAttention on MI355X (gfx950)
// B=2, S=2048, HID=4096, NH=32, NKV=8, HD=128, WINDOW=1024, THETA=10000
// Consolidated best-per-component build:
//   cvt1 (merged wqkvT + hs->bf16)
//   GEMM1: single-sync NIF3 256x192, grid 512  [best measured: 207 us]
//   rope_cvtwo (K-rope + woT)
//   attn: fused Q-RoPE, __expf softmax, pad-LDS  [from best 484-us build]
//   GEMM2: 8-phase NIF4 256x256, grid 256       [from best 484-us build]
// ---------------------------------------------------------------------------

typedef __attribute__((ext_vector_type(8))) short short8;       // bf16x8 frag
typedef __attribute__((ext_vector_type(4))) float f32x4;        // 16x16 acc
typedef __attribute__((ext_vector_type(16))) float f32x16;      // 32x32 acc
typedef __attribute__((ext_vector_type(4))) unsigned int u32x4; // 16B load
typedef __attribute__((ext_vector_type(4))) unsigned short u16x4;

__device__ __forceinline__ unsigned short f2bf(float f) {
  unsigned int u = __builtin_bit_cast(unsigned int, f);
  u = u + 0x7fffu + ((u >> 16) & 1u);   // round-to-nearest-even
  return (unsigned short)(u >> 16);
}
__device__ __forceinline__ float bf2f(unsigned short h) {
  unsigned int u = ((unsigned int)h) << 16;
  return __builtin_bit_cast(float, u);
}
__device__ __forceinline__ unsigned int cvtpk_bf16(float lo, float hi) {
  unsigned int r;
  asm("v_cvt_pk_bf16_f32 %0, %1, %2" : "=v"(r) : "v"(lo), "v"(hi));
  return r;
}

__device__ __forceinline__ void gload_lds16(const unsigned short* g, unsigned short* l) {
  __builtin_amdgcn_global_load_lds(
      (const __attribute__((address_space(1))) unsigned int*)g,
      (__attribute__((address_space(3))) unsigned int*)l, 16, 0, 0);
}

#define MFMA16(A, B, C) __builtin_amdgcn_mfma_f32_16x16x32_bf16((A), (B), (C), 0, 0, 0)
#define MFMA32(A, B, C) __builtin_amdgcn_mfma_f32_32x32x16_bf16((A), (B), (C), 0, 0, 0)
#define BC8(x) __builtin_bit_cast(short8, (x))

// ---------------------------------------------------------------------------
// merged: cvt_t(wqkv -> wqkvT) + cvt_plain(hs -> hsb)
// ---------------------------------------------------------------------------
__global__ __launch_bounds__(256) void cvt1(const float* __restrict__ hs,
                                            const float* __restrict__ wqkv,
                                            unsigned short* __restrict__ hsb,
                                            unsigned short* __restrict__ wT) {
  const int bid = blockIdx.x;
  if (bid < 24576) {
    __shared__ float t[32][33];
    const int c0 = (bid % 192) * 32, r0 = (bid / 192) * 32;  // R=4096, C=6144
    const int tx = threadIdx.x & 31, ty = threadIdx.x >> 5;
#pragma unroll
    for (int i = 0; i < 4; ++i)
      t[ty + i * 8][tx] = wqkv[(size_t)(r0 + ty + i * 8) * 6144 + c0 + tx];
    __syncthreads();
#pragma unroll
    for (int i = 0; i < 4; ++i)
      wT[(size_t)(c0 + ty + i * 8) * 4096 + r0 + tx] = f2bf(t[tx][ty + i * 8]);
  } else {
    const int i = ((bid - 24576) * 256 + threadIdx.x) * 4;
    f32x4 v = *(const f32x4*)(hs + i);
    u16x4 o;
#pragma unroll
    for (int j = 0; j < 4; ++j) o[j] = f2bf(v[j]);
    *(u16x4*)(hsb + i) = o;
  }
}

// ---------------------------------------------------------------------------
// merged: rope_k (K heads in qkv) + cvt_t(wo -> woT)
// ---------------------------------------------------------------------------
__global__ __launch_bounds__(256) void rope_cvtwo(unsigned short* __restrict__ qkv,
                                                  const int* __restrict__ pos,
                                                  const float* __restrict__ wo,
                                                  unsigned short* __restrict__ wT) {
  const int bid = blockIdx.x;
  if (bid < 8192) {
    const int idx = bid * 256 + threadIdx.x;   // < 4096*8*64
    const int d = idx & 63;
    const int hh = (idx >> 6) & 7;
    const int tok = idx >> 9;
    const int s = tok & 2047;
    unsigned short* p = qkv + (size_t)tok * 6144 + 4096 + hh * 128 + d;
    const float x1 = bf2f(p[0]);
    const float x2 = bf2f(p[64]);
    const float inv = exp2f(-(float)d * 0.2076205059304601f);
    const float ang = (float)pos[s] * inv;
    const float c = cosf(ang), sn = sinf(ang);
    p[0]  = f2bf(x1 * c - x2 * sn);
    p[64] = f2bf(x2 * c + x1 * sn);
  } else {
    __shared__ float t[32][33];
    const int b2 = bid - 8192;
    const int c0 = (b2 % 128) * 32, r0 = (b2 / 128) * 32;   // R=C=4096
    const int tx = threadIdx.x & 31, ty = threadIdx.x >> 5;
#pragma unroll
    for (int i = 0; i < 4; ++i)
      t[ty + i * 8][tx] = wo[(size_t)(r0 + ty + i * 8) * 4096 + c0 + tx];
    __syncthreads();
#pragma unroll
    for (int i = 0; i < 4; ++i)
      wT[(size_t)(c0 + ty + i * 8) * 4096 + r0 + tx] = f2bf(t[tx][ty + i * 8]);
  }
}

// ---------------------------------------------------------------------------
// GEMM1: single-sync-per-tile schedule (best measured: 207 us @ grid 512).
// Tile 256 x (NIF*64); 512 threads = 8 waves (2M x 4N).
// Loop: { vmcnt(0); s_barrier; issue ALL stage rounds for t+1; P0/P1/P2 }.
// ---------------------------------------------------------------------------
template <int NIF, int OUTF32>
__global__ __launch_bounds__(512, 2) void gemm_ss(const unsigned short* __restrict__ A,
                                                  const unsigned short* __restrict__ BT,
                                                  void* __restrict__ Cout,
                                                  int M, int N, int K) {
  constexpr int BUFE = 16384 + NIF * 4096;
  constexpr int NR = NIF + 4;
  __shared__ __align__(16) unsigned short lds[2][BUFE];
  const int tid = threadIdx.x;
  const int lane = tid & 63;
  const int w = tid >> 6;
  const int wr = w >> 2;
  const int wc = w & 3;
  const int g = lane >> 4;
  const int l15 = lane & 15;

  const int nwg = gridDim.x;
  const int cpx = nwg >> 3;
  const int bid = blockIdx.x;
  const int swz = (bid & 7) * cpx + (bid >> 3);
  const int MT = M >> 8;
  const int m0 = (swz % MT) * 256;
  const int n0 = (swz / MT) * (NIF * 64);

  const int lrow = lane >> 3;
  const int lcol = ((lane & 7) ^ lrow) * 8;
  const unsigned short* Asrc = A + (size_t)(m0 + w * 8 + lrow) * K + lcol;
  const unsigned short* Bsrc = BT + (size_t)(n0 + w * 8 + lrow) * K + lcol;

  f32x4 acc[8][NIF] = {};

  auto stage = [&](int buf, int t, int r) {
    if (r < NIF) {
      const int rb = r * 64;
      gload_lds16(Bsrc + (size_t)rb * K + t * 64,
                  &lds[buf][16384 + (rb + w * 8) * 64]);
    } else {
      const int j = r - NIF;
      const int rb = (j & 1) * 128 + ((j >> 1) & 1) * 64;
      gload_lds16(Asrc + (size_t)rb * K + t * 64,
                  &lds[buf][(rb + w * 8) * 64]);
    }
  };
  auto rdA = [&](int buf, int mi, int ks) {
    const int row = wr * 128 + mi * 16 + l15;
    const int cb = (ks * 64 + g * 16) ^ ((l15 & 7) << 4);
    return *(const u32x4*)((const char*)&lds[buf][0] + row * 128 + cb);
  };
  auto rdB = [&](int buf, int ni, int ks) {
    const int row = wc * (NIF * 16) + ni * 16 + l15;
    const int cb = (ks * 64 + g * 16) ^ ((l15 & 7) << 4);
    return *(const u32x4*)((const char*)&lds[buf][0] + 32768 + row * 128 + cb);
  };

#pragma unroll
  for (int r = 0; r < NR; ++r) stage(0, 0, r);

  const int NT = K >> 6;
  for (int t = 0; t < NT; ++t) {
    const int cb_ = t & 1, nb_ = cb_ ^ 1;

    asm volatile("s_waitcnt vmcnt(0)" ::: "memory");
    __builtin_amdgcn_s_barrier();
    asm volatile("" ::: "memory");
    if (t + 1 < NT) {
#pragma unroll
      for (int r = 0; r < NR; ++r) stage(nb_, t + 1, r);
    }

    u32x4 bfr[NIF][2];
#pragma unroll
    for (int ni = 0; ni < NIF; ++ni) {
      bfr[ni][0] = rdB(cb_, ni, 0);
      bfr[ni][1] = rdB(cb_, ni, 1);
    }

    {
      u32x4 af[3][2];
#pragma unroll
      for (int mi = 0; mi < 3; ++mi) {
        af[mi][0] = rdA(cb_, mi, 0);
        af[mi][1] = rdA(cb_, mi, 1);
      }
      __builtin_amdgcn_s_setprio(1);
#pragma unroll
      for (int mi = 0; mi < 3; ++mi)
#pragma unroll
        for (int ni = 0; ni < NIF; ++ni) {
          acc[mi][ni] = MFMA16(BC8(af[mi][0]), BC8(bfr[ni][0]), acc[mi][ni]);
          acc[mi][ni] = MFMA16(BC8(af[mi][1]), BC8(bfr[ni][1]), acc[mi][ni]);
        }
      __builtin_amdgcn_s_setprio(0);
    }
    __builtin_amdgcn_s_barrier();
    {
      u32x4 af[3][2];
#pragma unroll
      for (int mi = 0; mi < 3; ++mi) {
        af[mi][0] = rdA(cb_, 3 + mi, 0);
        af[mi][1] = rdA(cb_, 3 + mi, 1);
      }
      __builtin_amdgcn_s_setprio(1);
#pragma unroll
      for (int mi = 0; mi < 3; ++mi)
#pragma unroll
        for (int ni = 0; ni < NIF; ++ni) {
          acc[3 + mi][ni] = MFMA16(BC8(af[mi][0]), BC8(bfr[ni][0]), acc[3 + mi][ni]);
          acc[3 + mi][ni] = MFMA16(BC8(af[mi][1]), BC8(bfr[ni][1]), acc[3 + mi][ni]);
        }
      __builtin_amdgcn_s_setprio(0);
    }
    __builtin_amdgcn_s_barrier();
    {
      u32x4 af[2][2];
#pragma unroll
      for (int mi = 0; mi < 2; ++mi) {
        af[mi][0] = rdA(cb_, 6 + mi, 0);
        af[mi][1] = rdA(cb_, 6 + mi, 1);
      }
      __builtin_amdgcn_s_setprio(1);
#pragma unroll
      for (int mi = 0; mi < 2; ++mi)
#pragma unroll
        for (int ni = 0; ni < NIF; ++ni) {
          acc[6 + mi][ni] = MFMA16(BC8(af[mi][0]), BC8(bfr[ni][0]), acc[6 + mi][ni]);
          acc[6 + mi][ni] = MFMA16(BC8(af[mi][1]), BC8(bfr[ni][1]), acc[6 + mi][ni]);
        }
      __builtin_amdgcn_s_setprio(0);
    }
  }

  const int crow0 = m0 + wr * 128;
  const int ccol0 = n0 + wc * (NIF * 16);
#pragma unroll
  for (int mi = 0; mi < 8; ++mi)
#pragma unroll
    for (int ni = 0; ni < NIF; ++ni)
#pragma unroll
      for (int r = 0; r < 4; ++r) {
        const size_t idx =
            (size_t)(crow0 + mi * 16 + g * 4 + r) * N + (ccol0 + ni * 16 + l15);
        if constexpr (OUTF32) ((float*)Cout)[idx] = acc[mi][ni][r];
        else ((unsigned short*)Cout)[idx] = f2bf(acc[mi][ni][r]);
      }
}

// ---------------------------------------------------------------------------
// GEMM2: 8-phase template (from the 484-us build). NIF=4, grid 256.
// Phases P0-P3, counted vmcnt(4)@P1 / vmcnt(2)@P3, sched_barrier pins.
// ---------------------------------------------------------------------------
template <int NIF, int OUTF32>
__global__ __launch_bounds__(512, 2) void gemm_p4(const unsigned short* __restrict__ A,
                                                  const unsigned short* __restrict__ BT,
                                                  void* __restrict__ Cout,
                                                  int M, int N, int K) {
  constexpr int BUFE = 16384 + NIF * 4096;
  constexpr int NR = NIF + 4;
  __shared__ __align__(16) unsigned short lds[2][BUFE];
  const int tid = threadIdx.x;
  const int lane = tid & 63;
  const int w = tid >> 6;
  const int wr = w >> 2;
  const int wc = w & 3;
  const int g = lane >> 4;
  const int l15 = lane & 15;

  const int nwg = gridDim.x;
  const int cpx = nwg >> 3;
  const int bid = blockIdx.x;
  const int swz = (bid & 7) * cpx + (bid >> 3);
  const int MT = M >> 8;
  const int m0 = (swz % MT) * 256;
  const int n0 = (swz / MT) * (NIF * 64);

  const int lrow = lane >> 3;
  const int lcol = ((lane & 7) ^ lrow) * 8;
  const unsigned short* Asrc = A + (size_t)(m0 + w * 8 + lrow) * K + lcol;
  const unsigned short* Bsrc = BT + (size_t)(n0 + w * 8 + lrow) * K + lcol;

  f32x4 acc[8][NIF] = {};

  auto stage = [&](int buf, int t, int r) {
    if (r < NIF) {
      const int rb = r * 64;
      gload_lds16(Bsrc + (size_t)rb * K + t * 64,
                  &lds[buf][16384 + (rb + w * 8) * 64]);
    } else {
      const int j = r - NIF;
      const int rb = (j & 1) * 128 + ((j >> 1) & 1) * 64;
      gload_lds16(Asrc + (size_t)rb * K + t * 64,
                  &lds[buf][(rb + w * 8) * 64]);
    }
  };
  auto rdA = [&](int buf, int mi, int ks) {
    const int row = wr * 128 + mi * 16 + l15;
    const int cb = (ks * 64 + g * 16) ^ ((l15 & 7) << 4);
    return *(const u32x4*)((const char*)&lds[buf][0] + row * 128 + cb);
  };
  auto rdB = [&](int buf, int ni, int ks) {
    const int row = wc * (NIF * 16) + ni * 16 + l15;
    const int cb = (ks * 64 + g * 16) ^ ((l15 & 7) << 4);
    return *(const u32x4*)((const char*)&lds[buf][0] + 32768 + row * 128 + cb);
  };

#pragma unroll
  for (int r = 0; r < NR; ++r) stage(0, 0, r);
  asm volatile("s_waitcnt vmcnt(2)" ::: "memory");
  __builtin_amdgcn_sched_barrier(0);
  __builtin_amdgcn_s_barrier();

  const int NT = K >> 6;
  for (int t = 0; t < NT; ++t) {
    const int cb_ = t & 1, nb_ = cb_ ^ 1;
    const bool pre = (t + 1 < NT);
    u32x4 bfr[NIF][2];

    // ---------------- P0 : mi 0,1 (+ all B frags) ----------------
    {
#pragma unroll
      for (int ni = 0; ni < NIF; ++ni) {
        bfr[ni][0] = rdB(cb_, ni, 0);
        bfr[ni][1] = rdB(cb_, ni, 1);
      }
      u32x4 a00 = rdA(cb_, 0, 0), a01 = rdA(cb_, 0, 1);
      u32x4 a10 = rdA(cb_, 1, 0), a11 = rdA(cb_, 1, 1);
      if (pre) { stage(nb_, t + 1, 0); stage(nb_, t + 1, 1); }
      __builtin_amdgcn_sched_barrier(0);
      __builtin_amdgcn_s_barrier();
      asm volatile("s_waitcnt lgkmcnt(0)" ::: "memory");
      __builtin_amdgcn_sched_barrier(0);
      __builtin_amdgcn_s_setprio(1);
#pragma unroll
      for (int ni = 0; ni < NIF; ++ni) {
        acc[0][ni] = MFMA16(BC8(a00), BC8(bfr[ni][0]), acc[0][ni]);
        acc[0][ni] = MFMA16(BC8(a01), BC8(bfr[ni][1]), acc[0][ni]);
        acc[1][ni] = MFMA16(BC8(a10), BC8(bfr[ni][0]), acc[1][ni]);
        acc[1][ni] = MFMA16(BC8(a11), BC8(bfr[ni][1]), acc[1][ni]);
      }
      __builtin_amdgcn_s_setprio(0);
      __builtin_amdgcn_sched_barrier(0);
      __builtin_amdgcn_s_barrier();
    }
    // ---------------- P1 : mi 2,3 ----------------
    {
      u32x4 a00 = rdA(cb_, 2, 0), a01 = rdA(cb_, 2, 1);
      u32x4 a10 = rdA(cb_, 3, 0), a11 = rdA(cb_, 3, 1);
      if (pre) {
        stage(nb_, t + 1, 2); stage(nb_, t + 1, 3);
        asm volatile("s_waitcnt vmcnt(4)" ::: "memory");
      } else {
        asm volatile("s_waitcnt vmcnt(0)" ::: "memory");
      }
      __builtin_amdgcn_sched_barrier(0);
      __builtin_amdgcn_s_barrier();
      asm volatile("s_waitcnt lgkmcnt(0)" ::: "memory");
      __builtin_amdgcn_sched_barrier(0);
      __builtin_amdgcn_s_setprio(1);
#pragma unroll
      for (int ni = 0; ni < NIF; ++ni) {
        acc[2][ni] = MFMA16(BC8(a00), BC8(bfr[ni][0]), acc[2][ni]);
        acc[2][ni] = MFMA16(BC8(a01), BC8(bfr[ni][1]), acc[2][ni]);
        acc[3][ni] = MFMA16(BC8(a10), BC8(bfr[ni][0]), acc[3][ni]);
        acc[3][ni] = MFMA16(BC8(a11), BC8(bfr[ni][1]), acc[3][ni]);
      }
      __builtin_amdgcn_s_setprio(0);
      __builtin_amdgcn_sched_barrier(0);
      __builtin_amdgcn_s_barrier();
    }
    // ---------------- P2 : mi 4,5 ----------------
    {
      u32x4 a00 = rdA(cb_, 4, 0), a01 = rdA(cb_, 4, 1);
      u32x4 a10 = rdA(cb_, 5, 0), a11 = rdA(cb_, 5, 1);
      if (pre) { stage(nb_, t + 1, 4); stage(nb_, t + 1, 5); }
      __builtin_amdgcn_sched_barrier(0);
      __builtin_amdgcn_s_barrier();
      asm volatile("s_waitcnt lgkmcnt(0)" ::: "memory");
      __builtin_amdgcn_sched_barrier(0);
      __builtin_amdgcn_s_setprio(1);
#pragma unroll
      for (int ni = 0; ni < NIF; ++ni) {
        acc[4][ni] = MFMA16(BC8(a00), BC8(bfr[ni][0]), acc[4][ni]);
        acc[4][ni] = MFMA16(BC8(a01), BC8(bfr[ni][1]), acc[4][ni]);
        acc[5][ni] = MFMA16(BC8(a10), BC8(bfr[ni][0]), acc[5][ni]);
        acc[5][ni] = MFMA16(BC8(a11), BC8(bfr[ni][1]), acc[5][ni]);
      }
      __builtin_amdgcn_s_setprio(0);
      __builtin_amdgcn_sched_barrier(0);
      __builtin_amdgcn_s_barrier();
    }
    // ---------------- P3 : mi 6,7 ----------------
    {
      u32x4 a00 = rdA(cb_, 6, 0), a01 = rdA(cb_, 6, 1);
      u32x4 a10 = rdA(cb_, 7, 0), a11 = rdA(cb_, 7, 1);
      if (pre) {
        stage(nb_, t + 1, 6);
        if (NR == 8) stage(nb_, t + 1, 7);
        asm volatile("s_waitcnt vmcnt(2)" ::: "memory");
      }
      __builtin_amdgcn_sched_barrier(0);
      __builtin_amdgcn_s_barrier();
      asm volatile("s_waitcnt lgkmcnt(0)" ::: "memory");
      __builtin_amdgcn_sched_barrier(0);
      __builtin_amdgcn_s_setprio(1);
#pragma unroll
      for (int ni = 0; ni < NIF; ++ni) {
        acc[6][ni] = MFMA16(BC8(a00), BC8(bfr[ni][0]), acc[6][ni]);
        acc[6][ni] = MFMA16(BC8(a01), BC8(bfr[ni][1]), acc[6][ni]);
        acc[7][ni] = MFMA16(BC8(a10), BC8(bfr[ni][0]), acc[7][ni]);
        acc[7][ni] = MFMA16(BC8(a11), BC8(bfr[ni][1]), acc[7][ni]);
      }
      __builtin_amdgcn_s_setprio(0);
      __builtin_amdgcn_sched_barrier(0);
      __builtin_amdgcn_s_barrier();
    }
  }

  const int crow0 = m0 + wr * 128;
  const int ccol0 = n0 + wc * (NIF * 16);
#pragma unroll
  for (int mi = 0; mi < 8; ++mi)
#pragma unroll
    for (int ni = 0; ni < NIF; ++ni)
#pragma unroll
      for (int r = 0; r < 4; ++r) {
        const size_t idx =
            (size_t)(crow0 + mi * 16 + g * 4 + r) * N + (ccol0 + ni * 16 + l15);
        if constexpr (OUTF32) ((float*)Cout)[idx] = acc[mi][ni][r];
        else ((unsigned short*)Cout)[idx] = f2bf(acc[mi][ni][r]);
      }
}

// ---------------------------------------------------------------------------
// Flash attention, GQA, causal + sliding window 1024, fused Q-RoPE.
// (the version from the 484-us build: __expf softmax, __syncthreads, pad-LDS)
// ---------------------------------------------------------------------------
__global__ __launch_bounds__(512, 2) void attn_kernel(const unsigned short* __restrict__ qkv,
                                                      unsigned short* __restrict__ aout,
                                                      const int* __restrict__ pos) {
  __shared__ __align__(16) unsigned short smem[35840];   // 2 buffers, 70 KiB

  const int tid = threadIdx.x;
  const int lane = tid & 63;
  const int w = tid >> 6;
  const int hi = lane >> 5;
  const int l31 = lane & 31;
  const int q0 = blockIdx.x * 256;
  const int h = blockIdx.y;
  const int b = blockIdx.z;
  const int kh = h >> 2;
  const size_t tokbase = (size_t)b * 2048;
  const int qw0 = q0 + w * 32;
  const int qg = qw0 + l31;

  // ---- Q fragments + fused NeoX RoPE (pairs (d, d+64) are lane-local) ----
  short8 qf[8];
  {
    const unsigned short* qp = qkv + (tokbase + qg) * 6144 + h * 128;
#pragma unroll
    for (int ks8 = 0; ks8 < 8; ++ks8)
      qf[ks8] = BC8(*(const u32x4*)(qp + ks8 * 16 + hi * 8));
    const float fp = (float)pos[qg];
#pragma unroll
    for (int ks8 = 0; ks8 < 4; ++ks8)
#pragma unroll
      for (int j = 0; j < 8; ++j) {
        const int d = ks8 * 16 + hi * 8 + j;
        const float x1 = bf2f((unsigned short)qf[ks8][j]);
        const float x2 = bf2f((unsigned short)qf[ks8 + 4][j]);
        const float ang = fp * exp2f(-(float)d * 0.2076205059304601f);
        float c, sn;
        __sincosf(ang, &sn, &c);
        qf[ks8][j]     = (short)f2bf(x1 * c - x2 * sn);
        qf[ks8 + 4][j] = (short)f2bf(x2 * c + x1 * sn);
      }
  }

  const int c0key = tid >> 4, c0col = tid & 15;
  const int c1key = (tid + 512) >> 4, c1col = tid & 15;

  u32x4 kreg[2], vreg[2];
  const unsigned short* kvK = qkv + tokbase * 6144 + 4096 + kh * 128;

  const int t0 = (q0 >= 1024 ? (q0 - 1023) >> 6 : 0);
  const int t1 = (q0 + 255) >> 6;

  {
    const unsigned short* kb = kvK + (size_t)(t0 * 64) * 6144;
    kreg[0] = *(const u32x4*)(kb + (size_t)c0key * 6144 + c0col * 8);
    kreg[1] = *(const u32x4*)(kb + (size_t)c1key * 6144 + c1col * 8);
    vreg[0] = *(const u32x4*)(kb + (size_t)c0key * 6144 + 1024 + c0col * 8);
    vreg[1] = *(const u32x4*)(kb + (size_t)c1key * 6144 + 1024 + c1col * 8);
  }

  float m_run = -1e30f, l_run = 0.0f;
  f32x16 o_acc[4] = {};

  for (int kt = t0; kt <= t1; ++kt) {
    const int cur = (kt - t0) & 1;
    unsigned short* kdst = &smem[(cur)*17920];
    unsigned short* vdst = kdst + 8704;

    if (kt == t0) {
      *(u32x4*)&kdst[c0key * 136 + c0col * 8] = kreg[0];
      *(u32x4*)&kdst[c1key * 136 + c1col * 8] = kreg[1];
#pragma unroll
      for (int e = 0; e < 8; ++e) {
        const int e0 = (e + c0col) & 7;
        const int e1 = (e + c1col) & 7;
        vdst[(c0col * 8 + e0) * 72 + c0key] =
            (unsigned short)(vreg[0][e0 >> 1] >> ((e0 & 1) * 16));
        vdst[(c1col * 8 + e1) * 72 + c1key] =
            (unsigned short)(vreg[1][e1 >> 1] >> ((e1 & 1) * 16));
      }
      if (kt < t1) {
        const unsigned short* kb = kvK + (size_t)((kt + 1) * 64) * 6144;
        kreg[0] = *(const u32x4*)(kb + (size_t)c0key * 6144 + c0col * 8);
        kreg[1] = *(const u32x4*)(kb + (size_t)c1key * 6144 + c1col * 8);
        vreg[0] = *(const u32x4*)(kb + (size_t)c0key * 6144 + 1024 + c0col * 8);
        vreg[1] = *(const u32x4*)(kb + (size_t)c1key * 6144 + 1024 + c1col * 8);
      }
      __syncthreads();
    }

    if (kt < t1) {
      unsigned short* kdn = &smem[(cur ^ 1) * 17920];
      unsigned short* vdn = kdn + 8704;
      *(u32x4*)&kdn[c0key * 136 + c0col * 8] = kreg[0];
      *(u32x4*)&kdn[c1key * 136 + c1col * 8] = kreg[1];
#pragma unroll
      for (int e = 0; e < 8; ++e) {
        const int e0 = (e + c0col) & 7;
        const int e1 = (e + c1col) & 7;
        vdn[(c0col * 8 + e0) * 72 + c0key] =
            (unsigned short)(vreg[0][e0 >> 1] >> ((e0 & 1) * 16));
        vdn[(c1col * 8 + e1) * 72 + c1key] =
            (unsigned short)(vreg[1][e1 >> 1] >> ((e1 & 1) * 16));
      }
      if (kt + 2 <= t1) {
        const unsigned short* kb = kvK + (size_t)((kt + 2) * 64) * 6144;
        kreg[0] = *(const u32x4*)(kb + (size_t)c0key * 6144 + c0col * 8);
        kreg[1] = *(const u32x4*)(kb + (size_t)c1key * 6144 + c1col * 8);
        vreg[0] = *(const u32x4*)(kb + (size_t)c0key * 6144 + 1024 + c0col * 8);
        vreg[1] = *(const u32x4*)(kb + (size_t)c1key * 6144 + 1024 + c1col * 8);
      }
    }

    const int ktb = kt * 64;
    if (ktb <= qw0 + 31 && ktb + 63 >= qw0 - 1023) {
      const unsigned short* kb = &smem[cur * 17920];
      const unsigned short* vb = kb + 8704;

      f32x16 s0 = {}, s1 = {};
      const int arow = l31 * 136 + hi * 8;
#pragma unroll
      for (int ks8 = 0; ks8 < 8; ++ks8) {
        u32x4 a0 = *(const u32x4*)&kb[arow + ks8 * 16];
        u32x4 a1 = *(const u32x4*)&kb[arow + 32 * 136 + ks8 * 16];
        s0 = MFMA32(BC8(a0), qf[ks8], s0);
        s1 = MFMA32(BC8(a1), qf[ks8], s1);
      }

      const float scale = 0.08838834764831845f;
      float pv[32];
      const bool need_mask = !(ktb + 63 <= qw0 && ktb >= qw0 - 992);
      if (need_mask) {
#pragma unroll
        for (int r = 0; r < 16; ++r) {
          const int key0 = ktb + ((r & 3) + 8 * (r >> 2) + 4 * hi);
          const int key1 = key0 + 32;
          pv[r]      = (key0 <= qg && qg - key0 < 1024) ? s0[r] * scale : -1e30f;
          pv[16 + r] = (key1 <= qg && qg - key1 < 1024) ? s1[r] * scale : -1e30f;
        }
      } else {
#pragma unroll
        for (int r = 0; r < 16; ++r) {
          pv[r] = s0[r] * scale;
          pv[16 + r] = s1[r] * scale;
        }
      }

      float tm = -1e30f;
#pragma unroll
      for (int i = 0; i < 32; ++i) tm = fmaxf(tm, pv[i]);
      tm = fmaxf(tm, __shfl_xor(tm, 32, 64));
      if (__any(tm > m_run + 8.0f)) {
        const float mn = fmaxf(fmaxf(m_run, tm), -1e20f);
        const float scl = __expf(m_run - mn);
#pragma unroll
        for (int d = 0; d < 4; ++d) o_acc[d] *= scl;
        l_run *= scl;
        m_run = mn;
      }
      float lsum = 0.0f;
#pragma unroll
      for (int i = 0; i < 32; ++i) {
        pv[i] = __expf(pv[i] - m_run);
        lsum += pv[i];
      }
      l_run += lsum + __shfl_xor(lsum, 32, 64);

      u32x4 paf[4];
#pragma unroll
      for (int ks = 0; ks < 4; ++ks) {
        const int base = (ks >> 1) * 16 + (ks & 1) * 8;
        auto rA = __builtin_amdgcn_permlane32_swap(
            (int)cvtpk_bf16(pv[base + 0], pv[base + 1]),
            (int)cvtpk_bf16(pv[base + 4], pv[base + 5]), false, false);
        auto rB = __builtin_amdgcn_permlane32_swap(
            (int)cvtpk_bf16(pv[base + 2], pv[base + 3]),
            (int)cvtpk_bf16(pv[base + 6], pv[base + 7]), false, false);
        paf[ks][0] = (unsigned int)rA[0];
        paf[ks][1] = (unsigned int)rB[0];
        paf[ks][2] = (unsigned int)rA[1];
        paf[ks][3] = (unsigned int)rB[1];
      }

#pragma unroll
      for (int dblk = 0; dblk < 4; ++dblk) {
        const int vrow = (dblk * 32 + l31) * 72 + hi * 8;
#pragma unroll
        for (int ks = 0; ks < 4; ++ks) {
          u32x4 vf = *(const u32x4*)&vb[vrow + ks * 16];
          o_acc[dblk] = MFMA32(BC8(vf), BC8(paf[ks]), o_acc[dblk]);
        }
      }
    }

    __syncthreads();
  }

  const float rl = 1.0f / l_run;
  unsigned short* ob = &smem[w * 4352];
#pragma unroll
  for (int dblk = 0; dblk < 4; ++dblk)
#pragma unroll
    for (int rq = 0; rq < 4; ++rq) {
      u16x4 pk;
#pragma unroll
      for (int i = 0; i < 4; ++i) pk[i] = f2bf(o_acc[dblk][rq * 4 + i] * rl);
      *(u16x4*)&ob[l31 * 136 + dblk * 32 + rq * 8 + hi * 4] = pk;
    }
  __syncthreads();

  unsigned short* gout = aout + (tokbase + q0 + w * 32) * 4096 + h * 128;
#pragma unroll
  for (int r4 = 0; r4 < 8; ++r4) {
    const int row = r4 * 4 + (lane >> 4);
    u32x4 val = *(const u32x4*)&ob[row * 136 + (lane & 15) * 8];
    *(u32x4*)(gout + (size_t)row * 4096 + (lane & 15) * 8) = val;
  }
}

// ---------------------------------------------------------------------------
// launch
// ---------------------------------------------------------------------------
extern "C" void kernel_launch(void* const* d_in, const int* in_sizes, int n_in,
                              void* d_out, int out_size, void* d_ws, size_t ws_size,
                              hipStream_t stream) {
  (void)in_sizes; (void)n_in; (void)out_size; (void)ws_size;
  const float* hs   = (const float*)d_in[0];   // [2,2048,4096]
  const float* wqkv = (const float*)d_in[1];   // [4096,6144]
  const float* wo   = (const float*)d_in[2];   // [4096,4096]
  const int*   pos  = (const int*)d_in[3];     // [2048]
  float* out = (float*)d_out;                  // [2,2048,4096] fp32

  char* ws = (char*)d_ws;
  unsigned short* qkvb = (unsigned short*)ws;                // [4096][6144] bf16
  unsigned short* wT   = (unsigned short*)(ws + 50331648);   // weightT bf16
  unsigned short* hsb  = (unsigned short*)(ws + 100663296);  // [4096][4096] bf16

  cvt1<<<40960, 256, 0, stream>>>(hs, wqkv, hsb, wT);
  // GEMM1: single-sync NIF3 256x192, grid 512 = 2.0 CU-waves (207 us measured)
  gemm_ss<3, 0><<<512, 512, 0, stream>>>(hsb, wT, qkvb, 4096, 6144, 4096);
  rope_cvtwo<<<24576, 256, 0, stream>>>(qkvb, pos, wo, wT);
  attn_kernel<<<dim3(8, 32, 2), 512, 0, stream>>>(qkvb, hsb, pos);
  // GEMM2: 8-phase NIF4 256x256, grid 256 = 1.0 CU-wave (484-build config)
  gemm_p4<4, 1><<<256, 512, 0, stream>>>(hsb, wT, out, 4096, 4096, 4096);
}